// Round 1
// baseline (128.413 us; speedup 1.0000x reference)
//
#include <hip/hip_runtime.h>

// Fused: bicubic 2x upsample (antialias no-op) -> leaky_relu(0.01) -> bicubic
// antialiased 2x downsample.  NHWC f32, B=16, H=W=128, C=128.
//
// One block: (batch b, 8-row output strip, 16-channel chunk, all 128 cols).
// 256 threads = 16 channels x 16 col-groups (8 output cols each).
// Stream fine rows fy; coarse rows in a 5-row register ring; the vertical-
// upsample row is shared across col-groups through a double-buffered LDS row;
// vertical downsample scatters into 5 rotating register accumulators.

#define HH 128
#define WW 128
#define CC 128
#define RS 8      // output rows per strip
#define CH 16     // channels per block
#define PAD 129   // LDS row stride (odd -> 2-way bank aliasing == free)

__device__ __forceinline__ double keys_cubic(double x) {
  // JAX _fill_keys_cubic_kernel (a = -0.5)
  if (x >= 2.0) return 0.0;
  if (x >= 1.0) return ((-0.5 * x + 2.5) * x - 4.0) * x + 2.0;
  return (1.5 * x - 2.5) * x * x + 1.0;
}

__global__ __launch_bounds__(256) void fused_updown_kernel(
    const float* __restrict__ x, float* __restrict__ out) {
  __shared__ __align__(16) float wUp[256][4];   // fine idx -> 4 taps @ st=((k+1)>>1)-2
  __shared__ __align__(16) float wDn[128][8];   // out idx  -> 8 taps @ st=2j-3
  __shared__ float rowv[2][CH][PAD];            // double-buffered vert-upsampled row

  const int tid = threadIdx.x;

  // ---- build renormalized-truncation weight tables (match jax.image.resize) ----
  {
    const int k = tid;                      // 0..255
    const double q = 0.5 * k - 0.25;        // sample_f = (k+0.5)/2 - 0.5
    const int st = ((k + 1) >> 1) - 2;
    double wr[4];
    double s = 0.0;
#pragma unroll
    for (int i = 0; i < 4; ++i) {
      const int col = st + i;
      double w = 0.0;
      if (col >= 0 && col <= 127) w = keys_cubic(fabs((double)col - q));
      wr[i] = w;
      s += w;
    }
    const double inv = 1.0 / s;
#pragma unroll
    for (int i = 0; i < 4; ++i) wUp[k][i] = (float)(wr[i] * inv);
  }
  if (tid < 128) {
    const int j = tid;
    const double p = 2.0 * j + 0.5;         // sample_f = (j+0.5)*2 - 0.5
    const int st = 2 * j - 3;
    double wr[8];
    double s = 0.0;
#pragma unroll
    for (int i = 0; i < 8; ++i) {
      const int col = st + i;
      double w = 0.0;
      if (col >= 0 && col <= 255) w = keys_cubic(0.5 * fabs((double)col - p));
      wr[i] = w;
      s += w;
    }
    const double inv = 1.0 / s;
#pragma unroll
    for (int i = 0; i < 8; ++i) wDn[j][i] = (float)(wr[i] * inv);
  }
  __syncthreads();

  const int bid = blockIdx.x;
  const int b = bid & 15;            // low bits: batch (keeps line-sharing chunks
  const int strip = (bid >> 4) & 15; // and halo-sharing strips on the same XCD)
  const int chunk = bid >> 8;        // 0..7
  const int oy0 = strip * RS;
  const int c0 = chunk * CH;
  const int c = tid & 15;            // channel within chunk (lane-contiguous)
  const int g = tid >> 4;            // col group 0..15
  const int col0 = g * 8;

  const float* xbase = x + (size_t)b * (HH * WW * CC) + (size_t)col0 * CC + (c0 + c);
  float* obase = out + (size_t)b * (HH * WW * CC) + (size_t)col0 * CC + (c0 + c);

  float A0[8], A1[8], A2[8], A3[8], A4[8];   // rotating out-row accumulators
#pragma unroll
  for (int i = 0; i < 8; ++i) { A0[i]=0.f; A1[i]=0.f; A2[i]=0.f; A3[i]=0.f; A4[i]=0.f; }

  float r0[8], r1[8], r2[8], r3[8], r4[8];   // coarse-row register ring

  auto load_row = [&](float (&d)[8], int row) {
    row = row < 0 ? 0 : (row > 127 ? 127 : row);
    const float* p = xbase + (size_t)row * (WW * CC);
#pragma unroll
    for (int j = 0; j < 8; ++j) d[j] = p[j * CC];
  };

  const int m0 = oy0 - 2;
  load_row(r0, m0 - 2);
  load_row(r1, m0 - 1);
  load_row(r2, m0);
  load_row(r3, m0 + 1);
  load_row(r4, m0 + 2);

  const int k0 = 16 * g - 3;   // first fine col this thread needs

  auto process_row = [&](int fy, const float (&t0)[8], const float (&t1)[8],
                         const float (&t2)[8], const float (&t3)[8],
                         float (&B0)[8], float (&B1)[8], float (&B2)[8], float (&B3)[8],
                         int oyBase, int tapBase) {
    if (fy < 0 || fy > 255) return;          // block-uniform skip
    const int slot = fy & 1;                  // consecutive valid fy alternate slots
    const float4 wv = *(const float4*)wUp[fy];
    float v[16];                              // row_v at cols col0-4 .. col0+11
#pragma unroll
    for (int j2 = 0; j2 < 8; ++j2)
      v[4 + j2] = wv.x * t0[j2] + wv.y * t1[j2] + wv.z * t2[j2] + wv.w * t3[j2];
#pragma unroll
    for (int j2 = 0; j2 < 8; ++j2) rowv[slot][c][col0 + j2] = v[4 + j2];
    __syncthreads();
#pragma unroll
    for (int i = 0; i < 4; ++i) {
      int cl = col0 - 4 + i; cl = cl < 0 ? 0 : cl;         // clamped halo (finite,
      v[i] = rowv[slot][c][cl];                            // only ever hit with w=0)
      int cr = col0 + 8 + i; cr = cr > 127 ? 127 : cr;
      v[12 + i] = rowv[slot][c][cr];
    }
    // horizontal upsample + leaky relu, fine cols k0 .. k0+21
    float f[22];
#pragma unroll
    for (int u = 0; u < 22; ++u) {
      const int stL = (u >> 1) + 1;          // static v-index base
      const int k = k0 + u;
      float4 w;
      if ((unsigned)k < 3u || (unsigned)(255 - k) < 3u) {
        w = *(const float4*)wUp[k];          // boundary fine cols (g==0 / g==15 only)
      } else {
        w = (u & 1) ? make_float4(-0.0234375f, 0.2265625f, 0.8671875f, -0.0703125f)
                    : make_float4(-0.0703125f, 0.8671875f, 0.2265625f, -0.0234375f);
      }
      const float t = w.x * v[stL] + w.y * v[stL + 1] + w.z * v[stL + 2] + w.w * v[stL + 3];
      f[u] = fmaxf(t, 0.01f * t);            // leaky_relu
    }
    // vertical-downsample weights for the 4 affected output rows (uniform)
    float wd0 = 0.f, wd1 = 0.f, wd2 = 0.f, wd3 = 0.f;
    { int oy = oyBase + 0; if (oy >= 0 && oy <= 127) wd0 = wDn[oy][tapBase]; }
    { int oy = oyBase + 1; if (oy >= 0 && oy <= 127) wd1 = wDn[oy][tapBase - 2]; }
    { int oy = oyBase + 2; if (oy >= 0 && oy <= 127) wd2 = wDn[oy][tapBase - 4]; }
    { int oy = oyBase + 3; if (oy >= 0 && oy <= 127) wd3 = wDn[oy][tapBase - 6]; }
    // horizontal downsample + scatter-accumulate
#pragma unroll
    for (int jj = 0; jj < 8; ++jj) {
      const int j = col0 + jj;
      float t;
      if (j < 2 || j > 125) {
        const float4 lo = *(const float4*)&wDn[j][0];
        const float4 hi = *(const float4*)&wDn[j][4];
        t = lo.x * f[2*jj]   + lo.y * f[2*jj+1] + lo.z * f[2*jj+2] + lo.w * f[2*jj+3]
          + hi.x * f[2*jj+4] + hi.y * f[2*jj+5] + hi.z * f[2*jj+6] + hi.w * f[2*jj+7];
      } else {
        t = -0.01171875f * f[2*jj]   - 0.03515625f * f[2*jj+1]
          +  0.11328125f * f[2*jj+2] + 0.43359375f * f[2*jj+3]
          +  0.43359375f * f[2*jj+4] + 0.11328125f * f[2*jj+5]
          -  0.03515625f * f[2*jj+6] - 0.01171875f * f[2*jj+7];
      }
      B0[jj] += wd0 * t;
      B1[jj] += wd1 * t;
      B2[jj] += wd2 * t;
      B3[jj] += wd3 * t;
    }
  };

  for (int t = 0; t < 12; ++t) {
    const int m = m0 + t;
    if (t > 0) {
#pragma unroll
      for (int i = 0; i < 8; ++i) { r0[i]=r1[i]; r1[i]=r2[i]; r2[i]=r3[i]; r3[i]=r4[i]; }
      load_row(r4, m + 2);                   // consumed by the odd fine row below
    }
    // even fine row 2m: taps rows m-2..m+1, feeds oy = m-2..m+1 (taps 7,5,3,1)
    if (t >= 1) process_row(2 * m, r0, r1, r2, r3, A0, A1, A2, A3, m - 2, 7);
    // odd fine row 2m+1: taps rows m-1..m+2, feeds oy = m-1..m+2 (taps 6,4,2,0)
    if (t <= 10) process_row(2 * m + 1, r1, r2, r3, r4, A1, A2, A3, A4, m - 1, 6);

    const int oyC = m - 2;                   // out row completed this step
    if (oyC >= oy0) {
      float* op = obase + (size_t)oyC * (WW * CC);
#pragma unroll
      for (int jj = 0; jj < 8; ++jj) op[jj * CC] = A0[jj];
    }
#pragma unroll
    for (int i = 0; i < 8; ++i) { A0[i]=A1[i]; A1[i]=A2[i]; A2[i]=A3[i]; A3[i]=A4[i]; A4[i]=0.f; }
  }
}

extern "C" void kernel_launch(void* const* d_in, const int* in_sizes, int n_in,
                              void* d_out, int out_size, void* d_ws, size_t ws_size,
                              hipStream_t stream) {
  const float* x = (const float*)d_in[0];
  float* o = (float*)d_out;
  dim3 grid(16 * 16 * 8);   // batch(16) x strips(16) x channel-chunks(8)
  dim3 block(256);
  hipLaunchKernelGGL(fused_updown_kernel, grid, block, 0, stream, x, o);
}